// Round 7
// baseline (358.429 us; speedup 1.0000x reference)
//
#include <hip/hip_runtime.h>

typedef unsigned short u16;
typedef __attribute__((ext_vector_type(8))) short short8;
typedef __attribute__((ext_vector_type(4))) float floatx4;
typedef __attribute__((ext_vector_type(2))) unsigned int uint2e;

#define MFMA16(a, b, c) __builtin_amdgcn_mfma_f32_16x16x32_bf16((a), (b), (c), 0, 0, 0)
#define LOG2E 1.44269504088896340736f

// B=4, C=128, I=64, N=4096. fp32 I/O; bf16 intermediates.
#define SZ_P ((size_t)4 * 64 * 4096)   // 1,048,576 el
#define NSP 4                           // split-K ways per branch

__device__ __forceinline__ float bf2f(u16 u) {
    union { unsigned int i; float f; } v; v.i = ((unsigned int)u) << 16; return v.f;
}
__device__ __forceinline__ u16 f2bf(float f) {
    union { float f; unsigned int i; } v; v.f = f;
    unsigned int r = v.i + 0x7fffu + ((v.i >> 16) & 1u);
    return (u16)(r >> 16);
}
// 2 fp32 -> packed bf16x2 (RNE), single instruction
__device__ __forceinline__ unsigned int cvtpk(float a, float b) {
    unsigned int r;
    asm("v_cvt_pk_bf16_f32 %0, %1, %2" : "=v"(r) : "v"(a), "v"(b));
    return r;
}
// gfx950 cross-lane swaps
__device__ __forceinline__ void plswap32(unsigned int &a, unsigned int &b) {
#if __has_builtin(__builtin_amdgcn_permlane32_swap)
    uint2e r = __builtin_amdgcn_permlane32_swap(a, b, false, false);
    a = r.x; b = r.y;
#else
    asm volatile("v_permlane32_swap_b32 %0, %1" : "+v"(a), "+v"(b));
#endif
}
__device__ __forceinline__ void plswap16(unsigned int &a, unsigned int &b) {
#if __has_builtin(__builtin_amdgcn_permlane16_swap)
    uint2e r = __builtin_amdgcn_permlane16_swap(a, b, false, false);
    a = r.x; b = r.y;
#else
    asm volatile("v_permlane16_swap_b32 %0, %1" : "+v"(a), "+v"(b));
#endif
}
// LDS XOR-granule swizzle: element offset of 16B-granule g (0..7) in row
// (stride 64 u16). Writes land here via pre-swizzled global source +
// linear global_load_lds; reads use this directly.
__device__ __forceinline__ int swz(int row, int g) {
    return row * 64 + (((g ^ (row & 7)) << 3));
}
// direct global->LDS 16B DMA (per-lane gsrc, wave-uniform lds base + lane*16)
__device__ __forceinline__ void gload16(const void* g, void* l) {
    __builtin_amdgcn_global_load_lds(
        (const __attribute__((address_space(1))) unsigned char*)g,
        (__attribute__((address_space(3))) unsigned char*)l, 16, 0, 0);
}

// ---------------------------------------------------------------------------
// P0: weights fp32 -> bf16. wbf: 6 x 8192 (wq0,wk0,wv0,wq1,wk1,wv1),
// wWl @49152 (4096), wW @53248 (8192). Total 61440 el.
// Also zeroes the 64 split-K fixup counters (in-stream: visible to k_flash).
// ---------------------------------------------------------------------------
__global__ __launch_bounds__(256) void k_prep_w(
    const float* __restrict__ w0, const float* __restrict__ w1,
    const float* __restrict__ w2, const float* __restrict__ w3,
    const float* __restrict__ w4, const float* __restrict__ w5,
    const float* __restrict__ wWl, const float* __restrict__ wW,
    u16* __restrict__ wbf, int* __restrict__ ctr)
{
    const int idx = blockIdx.x * 256 + threadIdx.x;
    if (blockIdx.x == 0 && threadIdx.x < 64) ctr[threadIdx.x] = 0;
    float v;
    if (idx < 49152) {
        const int j = idx >> 13, off = idx & 8191;
        const float* s = (j == 0) ? w0 : (j == 1) ? w1 : (j == 2) ? w2
                       : (j == 3) ? w3 : (j == 4) ? w4 : w5;
        v = s[off];
    } else if (idx < 53248) {
        v = wWl[idx - 49152];
    } else {
        v = wW[idx - 53248];
    }
    wbf[idx] = f2bf(v);
}

// ---------------------------------------------------------------------------
// K1: projections. Each block stages its x-tile ONCE (float4-vectorized
// loads) and emits q,k,v for BOTH branches. Q pre-scaled by log2e.
// q,k bf16 [B,N,I]; v bf16 [B,I,N]. grid (64, 4), 256 thr.
// ---------------------------------------------------------------------------
__global__ __launch_bounds__(256) void k_proj(
    const float* __restrict__ x, const float* __restrict__ mask,
    const u16* __restrict__ wbf,
    const float* __restrict__ bq0f, const float* __restrict__ bk0f,
    const float* __restrict__ bv0f,
    const float* __restrict__ bq1f, const float* __restrict__ bk1f,
    const float* __restrict__ bv1f,
    u16* __restrict__ q0, u16* __restrict__ k0, u16* __restrict__ v0,
    u16* __restrict__ q1, u16* __restrict__ k1, u16* __restrict__ v1)
{
    __shared__ __align__(16) u16 xt_s[64 * 136];  // [n][c] bf16, pad 128->136
    const int n0 = blockIdx.x * 64, b = blockIdx.y;

    const int t = threadIdx.x, w = t >> 6, lane = t & 63;
    const int quad = lane >> 4, l15 = lane & 15;
    const float* xb = x + ((size_t)b << 19);
    const float4* xb4 = (const float4*)xb;

    // 2048 float4 loads cover the 64n x 128c tile; scalar transpose writes.
    for (int idx = t; idx < 2048; idx += 256) {
        const int c = idx >> 4, n4 = (idx & 15) * 4;
        const float4 v4 = xb4[((size_t)c << 10) + (n0 >> 2) + (idx & 15)];
        xt_s[(n4 + 0) * 136 + c] = f2bf(v4.x);
        xt_s[(n4 + 1) * 136 + c] = f2bf(v4.y);
        xt_s[(n4 + 2) * 136 + c] = f2bf(v4.z);
        xt_s[(n4 + 3) * 136 + c] = f2bf(v4.w);
    }
    __syncthreads();

    short8 ax[4];
#pragma unroll
    for (int cc = 0; cc < 4; ++cc)
        ax[cc] = *(const short8*)&xt_s[(w * 16 + l15) * 136 + quad * 8 + cc * 32];

#pragma unroll
    for (int br = 0; br < 2; ++br) {
        const u16* wq = wbf + br * 24576;
        const u16* wk = wq + 8192;
        const u16* wv = wk + 8192;
        const float* bq = br ? bq1f : bq0f;
        const float* bk = br ? bk1f : bk0f;
        const float* bv = br ? bv1f : bv0f;
        u16* q = br ? q1 : q0;  u16* k = br ? k1 : k0;  u16* v = br ? v1 : v0;

        float mv[4] = {1.f, 1.f, 1.f, 1.f};
        if (br) {
#pragma unroll
            for (int r = 0; r < 4; ++r)
                mv[r] = mask[((size_t)b << 12) + n0 + w * 16 + quad * 4 + r];
        }

        // Q and K: D[n][i], all 4 i-column groups; Q scaled by log2e
#pragma unroll
        for (int qk = 0; qk < 2; ++qk) {
            const u16* wsel = qk ? wk : wq;
            const float* bb = qk ? bk : bq;
            u16* o = qk ? k : q;
            const float qscale = qk ? 1.0f : LOG2E;
#pragma unroll
            for (int ns = 0; ns < 4; ++ns) {
                floatx4 acc = {0.f, 0.f, 0.f, 0.f};
                const u16* wp = wsel + (ns * 16 + l15) * 128 + quad * 8;
#pragma unroll
                for (int cc = 0; cc < 4; ++cc)
                    acc = MFMA16(ax[cc], *(const short8*)(wp + cc * 32), acc);
                const float bias_i = bb[ns * 16 + l15];
#pragma unroll
                for (int r = 0; r < 4; ++r) {
                    const float val = (acc[r] + bias_i) * mv[r] * qscale;
                    o[((size_t)b << 18) + (size_t)(n0 + w * 16 + quad * 4 + r) * 64
                      + ns * 16 + l15] = f2bf(val);
                }
            }
        }

        // V: D[i][n], all 4 n-column groups
        short8 aw[4];
#pragma unroll
        for (int cc = 0; cc < 4; ++cc)
            aw[cc] = *(const short8*)(wv + (w * 16 + l15) * 128 + quad * 8 + cc * 32);
        float bvr[4];
#pragma unroll
        for (int r = 0; r < 4; ++r) bvr[r] = bv[w * 16 + quad * 4 + r];
#pragma unroll
        for (int ns = 0; ns < 4; ++ns) {
            floatx4 acc = {0.f, 0.f, 0.f, 0.f};
#pragma unroll
            for (int cc = 0; cc < 4; ++cc)
                acc = MFMA16(aw[cc],
                    *(const short8*)&xt_s[(ns * 16 + l15) * 136 + quad * 8 + cc * 32], acc);
#pragma unroll
            for (int r = 0; r < 4; ++r) {
                v[((size_t)b << 18) + ((size_t)(w * 16 + quad * 4 + r) << 12)
                  + n0 + ns * 16 + l15] = f2bf(acc[r] + bvr[r]);
            }
        }
    }
}

// ---------------------------------------------------------------------------
// K2: attention + fused split-K fixup epilogue.
// Main loop unchanged from R6 (P in registers, swizzled LDS via DMA,
// explicit vmcnt(0)+sched_barrier before barriers, MFMA-ones denominator).
// After num/den stores: release fence + per-tile atomic counter; the 8th
// (last) of the {2 br x 4 sp} contributing blocks for (b,tile) acquires and
// runs the full epilogue (split-K reduce + E1 + E2 + residual) for its
// 256-n tile — two 32-n subtiles at a time via the block's two 4-wave halves.
// Counters zeroed by k_prep_w each launch -> replay-deterministic.
// ---------------------------------------------------------------------------
__global__ __launch_bounds__(512, 4) void k_flash(
    const u16* __restrict__ Q0, const u16* __restrict__ K0,
    const u16* __restrict__ V0,
    const u16* __restrict__ Q1, const u16* __restrict__ K1,
    const u16* __restrict__ V1,
    u16* __restrict__ num, float* __restrict__ den,
    const u16* __restrict__ wbf, int* __restrict__ ctr,
    const float* __restrict__ gWl, const float* __restrict__ betaWl,
    const float* __restrict__ bW, const float* __restrict__ gW,
    const float* __restrict__ betaW,
    const float* __restrict__ x, float* __restrict__ out)
{
    constexpr int NIT = 4096 / NSP / 64;     // 16 j-iters per block

    // K dbuf @0,4096 | V dbuf @8192,12288 (stride-64 swizzled)
    // tail: O^T staging [wave][32][72]; fixup: 2 halves x {yl,ynl,yy}[32][72]
    __shared__ __align__(16) u16 smem[18432];
    __shared__ int elect_s;

    const int flat = blockIdx.x;
    const int g = flat & 31, tile = flat >> 5;
    const int b = g >> 3, br = (g >> 2) & 1, sp = g & 3;
    const int z = br * NSP + sp;
    const int qb = tile * 256;
    const size_t base = ((size_t)b << 18);
    const u16* Q = (br ? Q1 : Q0) + base;
    const u16* K = (br ? K1 : K0) + base;
    const u16* V = (br ? V1 : V0) + base;
    u16* numo = num + (size_t)z * SZ_P + base;
    float* deno = den + z * 16384 + b * 4096;

    const int t = threadIdx.x, w = t >> 6, lane = t & 63;
    const int quad = lane >> 4, l15 = lane & 15;
    const int pw = w * 32 * 72;

    // staging: lane covers row r0, pre-swizzled granule gx so that the
    // linear lane*16B LDS write of global_load_lds lands on swz(row,g).
    const int r0 = t >> 3;
    const int gx = (t & 7) ^ ((t >> 3) & 7);
    const u16* Kp0 = K + (size_t)r0 * 64 + gx * 8;
    const u16* Vp0 = V + ((size_t)r0 << 12) + gx * 8;
    u16* kw = smem + w * 512;          // wave-uniform LDS bases (buffer 0)
    u16* vw = smem + 8192 + w * 512;

    short8 aq[2][2];
#pragma unroll
    for (int t2 = 0; t2 < 2; ++t2)
#pragma unroll
        for (int s = 0; s < 2; ++s)
            aq[t2][s] = *(const short8*)(Q + (size_t)(qb + w * 32 + t2 * 16 + l15) * 64
                                         + s * 32 + quad * 8);

    floatx4 oacc[4][2];
#pragma unroll
    for (int it = 0; it < 4; ++it)
#pragma unroll
        for (int t2 = 0; t2 < 2; ++t2) oacc[it][t2] = (floatx4){0.f, 0.f, 0.f, 0.f};
    floatx4 dacc4[2];
    dacc4[0] = (floatx4){0.f, 0.f, 0.f, 0.f};
    dacc4[1] = (floatx4){0.f, 0.f, 0.f, 0.f};
    const short8 vone = {(short)0x3F80, (short)0x3F80, (short)0x3F80, (short)0x3F80,
                         (short)0x3F80, (short)0x3F80, (short)0x3F80, (short)0x3F80};

    const int roff = tile & (NIT - 1);
    const int m_beg = sp * (4096 / NSP);

    {   // prologue: fill buffer 0
        const int m0 = m_beg + (roff << 6);
        gload16(Kp0 + (size_t)m0 * 64, kw);
        gload16(Vp0 + m0, vw);
    }

    for (int j = 0; j < NIT; ++j) {
        const int cur = j & 1;
        // Drain this wave's outstanding LDS-DMA BEFORE the barrier; barrier
        // then guarantees all waves' DMA landed (compiler won't do this).
        asm volatile("s_waitcnt vmcnt(0)" ::: "memory");
        __builtin_amdgcn_sched_barrier(0);
        __syncthreads();
        if (j + 1 < NIT) {
            const int mn = m_beg + (((roff + j + 1) & (NIT - 1)) << 6);
            gload16(Kp0 + (size_t)mn * 64, kw + (cur ^ 1) * 4096);
            gload16(Vp0 + mn, vw + (cur ^ 1) * 4096);
        }
        const u16* kt = smem + cur * 4096;
        const u16* vt = smem + 8192 + cur * 4096;

        // Per s-chunk (32 m): S' = K Q^T tiles + exp2, pack bf16 in-register,
        // permlane-redistribute to PV B-fragments, then PV + denominator MFMAs.
#pragma unroll
        for (int s = 0; s < 2; ++s) {
            unsigned int w0[2][2], w1[2][2];   // [mtl][t2] packed (e0,e1),(e2,e3)
#pragma unroll
            for (int mtl = 0; mtl < 2; ++mtl) {
                const int mt = s * 2 + mtl;
                const int ko = swz(mt * 16 + l15, quad);
                const short8 ka0 = *(const short8*)(kt + ko);
                const short8 ka1 = *(const short8*)(kt + (ko ^ 32)); // granule quad^4
#pragma unroll
                for (int t2 = 0; t2 < 2; ++t2) {
                    floatx4 acc = {0.f, 0.f, 0.f, 0.f};
                    __builtin_amdgcn_s_setprio(1);
                    acc = MFMA16(ka0, aq[t2][0], acc);
                    acc = MFMA16(ka1, aq[t2][1], acc);
                    __builtin_amdgcn_s_setprio(0);
                    const float e0 = __builtin_amdgcn_exp2f(acc[0]);
                    const float e1 = __builtin_amdgcn_exp2f(acc[1]);
                    const float e2 = __builtin_amdgcn_exp2f(acc[2]);
                    const float e3 = __builtin_amdgcn_exp2f(acc[3]);
                    w0[mtl][t2] = cvtpk(e0, e1);
                    w1[mtl][t2] = cvtpk(e2, e3);
                }
            }
            short8 pb[2];
#pragma unroll
            for (int t2 = 0; t2 < 2; ++t2) {
                unsigned int a0 = w0[0][t2], b0 = w0[1][t2];
                unsigned int a1 = w1[0][t2], b1 = w1[1][t2];
                plswap32(a0, b0); plswap16(a0, b0);   // a0=d0, b0=d2
                plswap32(a1, b1); plswap16(a1, b1);   // a1=d1, b1=d3
                union { unsigned int u[4]; short8 s8; } cv;
                cv.u[0] = a0; cv.u[1] = a1; cv.u[2] = b0; cv.u[3] = b1;
                pb[t2] = cv.s8;
            }
            __builtin_amdgcn_s_setprio(1);
#pragma unroll
            for (int it = 0; it < 4; ++it) {
                const short8 va = *(const short8*)(vt + swz(it * 16 + l15, s * 4 + quad));
#pragma unroll
                for (int t2 = 0; t2 < 2; ++t2)
                    oacc[it][t2] = MFMA16(va, pb[t2], oacc[it][t2]);
            }
            // denominator: A=ones -> D[r][q] = sum_m P[m][q] (all r equal)
            dacc4[0] = MFMA16(vone, pb[0], dacc4[0]);
            dacc4[1] = MFMA16(vone, pb[1], dacc4[1]);
            __builtin_amdgcn_s_setprio(0);
        }
    }

    // denominator partials (every lane holds the full column sum; r's equal)
    if (quad == 0) {
#pragma unroll
        for (int t2 = 0; t2 < 2; ++t2)
            deno[qb + w * 32 + t2 * 16 + l15] = dacc4[t2][0];
    }

    // O^T (C: row=i-local, col=q-local) -> smem (reused) as [q-local][i]
    __syncthreads();   // all waves done with kt/vt before aliasing (no DMA pending)
#pragma unroll
    for (int it = 0; it < 4; ++it)
#pragma unroll
        for (int t2 = 0; t2 < 2; ++t2) {
            *(uint2*)&smem[pw + (t2 * 16 + l15) * 72 + it * 16 + quad * 4] =
                make_uint2(cvtpk(oacc[it][t2][0], oacc[it][t2][1]),
                           cvtpk(oacc[it][t2][2], oacc[it][t2][3]));
        }
    __syncthreads();
#pragma unroll
    for (int ch = t; ch < 2048; ch += 512) {
        const int row = ch >> 3, cg = ch & 7;
        *(short8*)(numo + (size_t)(qb + row) * 64 + cg * 8) =
            *(const short8*)&smem[(row >> 5) * 2304 + (row & 31) * 72 + cg * 8];
    }

    // ---- split-K fixup: last of the 8 blocks for (b,tile) runs epilogue ----
    __threadfence();                 // release: num/den stores device-visible
    __syncthreads();                 // all threads' stores+fences done
    if (t == 0) {
        const int old = atomicAdd(&ctr[b * 16 + tile], 1);
        elect_s = (old == 7);
    }
    __syncthreads();
    if (!elect_s) return;
    __threadfence();                 // acquire: see the other 7 blocks' data

    const int half = w >> 2, wl = w & 3, tl = t & 255;
    u16* yl_sE  = smem + half * 6912;    // per-half {yl, ynl, yy}[32][72]
    u16* ynl_sE = yl_sE + 2304;
    u16* yy_sE  = yl_sE + 4608;
    const float rsq = rsqrtf(1.0f + 1e-5f);
    const u16* wblW = wbf + 49152;
    const u16* wbW  = wbf + 53248;

    for (int nh8 = 0; nh8 < 4; ++nh8) {
        const int n0e = qb + (nh8 * 2 + half) * 32;
        const size_t ybase = base + (size_t)n0e * 64;

        {   // split-K reduce: 32 rows x 8 granules per half
            const int row = tl >> 3, cg = tl & 7;
            float dn = 0.f, dl = 0.f;
#pragma unroll
            for (int sp2 = 0; sp2 < NSP; ++sp2) {
                dn += den[sp2 * 16384 + b * 4096 + n0e + row];
                dl += den[(NSP + sp2) * 16384 + b * 4096 + n0e + row];
            }
            const float inl = 1.0f / dn, ilo = 1.0f / dl;
            float an[8] = {0, 0, 0, 0, 0, 0, 0, 0}, al[8] = {0, 0, 0, 0, 0, 0, 0, 0};
#pragma unroll
            for (int sp2 = 0; sp2 < NSP; ++sp2) {
                const short8 vn = *(const short8*)(num + (size_t)sp2 * SZ_P + ybase + row * 64 + cg * 8);
                const short8 vl = *(const short8*)(num + (size_t)(NSP + sp2) * SZ_P + ybase + row * 64 + cg * 8);
#pragma unroll
                for (int jj = 0; jj < 8; ++jj) {
                    an[jj] += bf2f((u16)vn[jj]);
                    al[jj] += bf2f((u16)vl[jj]);
                }
            }
            short8 ynl8, yl8;
#pragma unroll
            for (int jj = 0; jj < 8; ++jj) {
                ynl8[jj] = (short)f2bf(an[jj] * inl);
                yl8[jj]  = (short)f2bf(al[jj] * ilo);
            }
            *(short8*)&ynl_sE[row * 72 + cg * 8] = ynl8;
            *(short8*)&yl_sE[row * 72 + cg * 8] = yl8;
        }
        __syncthreads();

        // E1: yy[n][io] = bn(relu(wWl . y_l)) + y_nl   (two 16-row halves)
        {
            const short8 a0 = *(const short8*)(wblW + (wl * 16 + l15) * 64 + quad * 8);
            const short8 a1 = *(const short8*)(wblW + (wl * 16 + l15) * 64 + 32 + quad * 8);
            float sc[4], bt[4];
#pragma unroll
            for (int r = 0; r < 4; ++r) {
                const int io = wl * 16 + quad * 4 + r;
                sc[r] = gWl[io] * rsq;
                bt[r] = betaWl[io];
            }
#pragma unroll
            for (int nh = 0; nh < 2; ++nh) {
                floatx4 acc = {0.f, 0.f, 0.f, 0.f};
                const u16* bp_ = &yl_sE[(nh * 16 + l15) * 72 + quad * 8];
                acc = MFMA16(a0, *(const short8*)bp_, acc);
                acc = MFMA16(a1, *(const short8*)(bp_ + 32), acc);
#pragma unroll
                for (int r = 0; r < 4; ++r) {
                    const int io = wl * 16 + quad * 4 + r;
                    float val = fmaxf(acc[r], 0.f) * sc[r] + bt[r];
                    val += bf2f(ynl_sE[(nh * 16 + l15) * 72 + io]);
                    yy_sE[(nh * 16 + l15) * 72 + io] = f2bf(val);
                }
            }
        }
        __syncthreads();

        // E2: out[c][n] = bn(relu(wW . yy + bW)) + x
#pragma unroll
        for (int rb = 0; rb < 2; ++rb) {
            const int c0 = rb * 64 + wl * 16;
            const short8 a0 = *(const short8*)(wbW + (c0 + l15) * 64 + quad * 8);
            const short8 a1 = *(const short8*)(wbW + (c0 + l15) * 64 + 32 + quad * 8);
            float bs[4], sc[4], bt[4];
#pragma unroll
            for (int r = 0; r < 4; ++r) {
                const int c = c0 + quad * 4 + r;
                bs[r] = bW[c];
                sc[r] = gW[c] * rsq;
                bt[r] = betaW[c];
            }
#pragma unroll
            for (int nh = 0; nh < 2; ++nh) {
                floatx4 acc = {0.f, 0.f, 0.f, 0.f};
                const u16* bp_ = &yy_sE[(nh * 16 + l15) * 72 + quad * 8];
                acc = MFMA16(a0, *(const short8*)bp_, acc);
                acc = MFMA16(a1, *(const short8*)(bp_ + 32), acc);
#pragma unroll
                for (int r = 0; r < 4; ++r) {
                    const int c = c0 + quad * 4 + r;
                    float val = fmaxf(acc[r] + bs[r], 0.f) * sc[r] + bt[r];
                    const size_t xi = ((size_t)b << 19) + ((size_t)c << 12) + n0e + nh * 16 + l15;
                    out[xi] = val + x[xi];
                }
            }
        }
        __syncthreads();   // E1 of next subtile must not race next reduce's yl/ynl
    }
}

// ---------------------------------------------------------------------------
extern "C" void kernel_launch(void* const* d_in, const int* in_sizes, int n_in,
                              void* d_out, int out_size, void* d_ws, size_t ws_size,
                              hipStream_t stream) {
    const float* x      = (const float*)d_in[0];
    const float* mask   = (const float*)d_in[1];
    const float* wt_nl  = (const float*)d_in[2];  const float* bt_nl = (const float*)d_in[3];
    const float* wp_nl  = (const float*)d_in[4];  const float* bp_nl = (const float*)d_in[5];
    const float* wt_l   = (const float*)d_in[6];  const float* bt_l  = (const float*)d_in[7];
    const float* wp_l   = (const float*)d_in[8];  const float* bp_l  = (const float*)d_in[9];
    const float* wg_nl  = (const float*)d_in[10]; const float* bg_nl = (const float*)d_in[11];
    const float* wg_l   = (const float*)d_in[12]; const float* bg_l  = (const float*)d_in[13];
    const float* wW     = (const float*)d_in[14]; const float* bW    = (const float*)d_in[15];
    const float* gW     = (const float*)d_in[16]; const float* betaW = (const float*)d_in[17];
    const float* wWl    = (const float*)d_in[18]; const float* gWl   = (const float*)d_in[19];
    const float* betaWl = (const float*)d_in[20];

    // ws: wbf 120KB + 6 qkv (12.6MB) + num 2*NSP x 2MB (16.8MB) + den 512KB + ctr
    u16* ws  = (u16*)d_ws;
    u16* wbf = ws;                  // 61440
    u16* q0  = wbf + 61440;
    u16* k0  = q0 + SZ_P;
    u16* v0  = k0 + SZ_P;
    u16* q1  = v0 + SZ_P;
    u16* k1  = q1 + SZ_P;
    u16* v1  = k1 + SZ_P;
    u16* num = v1 + SZ_P;           // 2*NSP x SZ_P (z = br*NSP+sp)
    float* den = (float*)(num + (size_t)2 * NSP * SZ_P);  // 2*NSP x 16384 fp32
    int* ctr = (int*)(den + 2 * NSP * 16384);             // 64 fixup counters

    k_prep_w<<<dim3(240), 256, 0, stream>>>(wt_nl, wp_nl, wg_nl,
                                            wt_l, wp_l, wg_l, wWl, wW, wbf, ctr);
    k_proj<<<dim3(64, 4), 256, 0, stream>>>(x, mask, wbf,
        bt_nl, bp_nl, bg_nl, bt_l, bp_l, bg_l,
        q0, k0, v0, q1, k1, v1);
    k_flash<<<dim3(512), 512, 0, stream>>>(q0, k0, v0, q1, k1, v1, num, den,
                                           wbf, ctr, gWl, betaWl, bW, gW, betaW,
                                           x, (float*)d_out);
}

// Round 8
// 157.246 us; speedup vs baseline: 2.2794x; 2.2794x over previous
//
#include <hip/hip_runtime.h>

typedef unsigned short u16;
typedef __attribute__((ext_vector_type(8))) short short8;
typedef __attribute__((ext_vector_type(4))) float floatx4;
typedef __attribute__((ext_vector_type(2))) unsigned int uint2e;

#define MFMA16(a, b, c) __builtin_amdgcn_mfma_f32_16x16x32_bf16((a), (b), (c), 0, 0, 0)
#define LOG2E 1.44269504088896340736f

// B=4, C=128, I=64, N=4096. fp32 I/O; bf16 intermediates.
#define SZ_P ((size_t)4 * 64 * 4096)   // 1,048,576 el
#define NSP 4                           // split-K ways per branch

__device__ __forceinline__ float bf2f(u16 u) {
    union { unsigned int i; float f; } v; v.i = ((unsigned int)u) << 16; return v.f;
}
__device__ __forceinline__ u16 f2bf(float f) {
    union { float f; unsigned int i; } v; v.f = f;
    unsigned int r = v.i + 0x7fffu + ((v.i >> 16) & 1u);
    return (u16)(r >> 16);
}
// 2 fp32 -> packed bf16x2 (RNE), single instruction
__device__ __forceinline__ unsigned int cvtpk(float a, float b) {
    unsigned int r;
    asm("v_cvt_pk_bf16_f32 %0, %1, %2" : "=v"(r) : "v"(a), "v"(b));
    return r;
}
// gfx950 cross-lane swaps
__device__ __forceinline__ void plswap32(unsigned int &a, unsigned int &b) {
#if __has_builtin(__builtin_amdgcn_permlane32_swap)
    uint2e r = __builtin_amdgcn_permlane32_swap(a, b, false, false);
    a = r.x; b = r.y;
#else
    asm volatile("v_permlane32_swap_b32 %0, %1" : "+v"(a), "+v"(b));
#endif
}
__device__ __forceinline__ void plswap16(unsigned int &a, unsigned int &b) {
#if __has_builtin(__builtin_amdgcn_permlane16_swap)
    uint2e r = __builtin_amdgcn_permlane16_swap(a, b, false, false);
    a = r.x; b = r.y;
#else
    asm volatile("v_permlane16_swap_b32 %0, %1" : "+v"(a), "+v"(b));
#endif
}
// LDS XOR-granule swizzle: element offset of 16B-granule g (0..7) in row
// (stride 64 u16). Writes land here via pre-swizzled global source +
// linear global_load_lds; reads use this directly.
__device__ __forceinline__ int swz(int row, int g) {
    return row * 64 + (((g ^ (row & 7)) << 3));
}
// direct global->LDS 16B DMA (per-lane gsrc, wave-uniform lds base + lane*16)
__device__ __forceinline__ void gload16(const void* g, void* l) {
    __builtin_amdgcn_global_load_lds(
        (const __attribute__((address_space(1))) unsigned char*)g,
        (__attribute__((address_space(3))) unsigned char*)l, 16, 0, 0);
}

// ---------------------------------------------------------------------------
// P0: weights fp32 -> bf16. wbf: 6 x 8192 (wq0,wk0,wv0,wq1,wk1,wv1),
// wWl @49152 (4096), wW @53248 (8192). Total 61440 el.  [R2 version]
// ---------------------------------------------------------------------------
__global__ __launch_bounds__(256) void k_prep_w(
    const float* __restrict__ w0, const float* __restrict__ w1,
    const float* __restrict__ w2, const float* __restrict__ w3,
    const float* __restrict__ w4, const float* __restrict__ w5,
    const float* __restrict__ wWl, const float* __restrict__ wW,
    u16* __restrict__ wbf)
{
    const int idx = blockIdx.x * 256 + threadIdx.x;
    float v;
    if (idx < 49152) {
        const int j = idx >> 13, off = idx & 8191;
        const float* s = (j == 0) ? w0 : (j == 1) ? w1 : (j == 2) ? w2
                       : (j == 3) ? w3 : (j == 4) ? w4 : w5;
        v = s[off];
    } else if (idx < 53248) {
        v = wWl[idx - 49152];
    } else {
        v = wW[idx - 53248];
    }
    wbf[idx] = f2bf(v);
}

// ---------------------------------------------------------------------------
// K1: projections; z = branch*2 + ns-half; in-LDS x transpose; bf16 weights.
// Q pre-scaled by log2e. q,k bf16 [B,N,I]; v bf16 [B,I,N].  [R2 version —
// measured best total; per-block work small, 4x staging redundancy is cheaper
// than the merged variant's serialization (R3: +3.8 us)]
// ---------------------------------------------------------------------------
__global__ __launch_bounds__(256) void k_proj(
    const float* __restrict__ x, const float* __restrict__ mask,
    const u16* __restrict__ wbf,
    const float* __restrict__ bq0f, const float* __restrict__ bk0f,
    const float* __restrict__ bv0f,
    const float* __restrict__ bq1f, const float* __restrict__ bk1f,
    const float* __restrict__ bv1f,
    u16* __restrict__ q0, u16* __restrict__ k0, u16* __restrict__ v0,
    u16* __restrict__ q1, u16* __restrict__ k1, u16* __restrict__ v1)
{
    __shared__ __align__(16) u16 xt_s[64 * 136];  // [n][c] bf16, pad 128->136
    const int n0 = blockIdx.x * 64, b = blockIdx.y;
    const int br = blockIdx.z >> 1, half = blockIdx.z & 1;
    const u16* wq = wbf + br * 24576;
    const u16* wk = wq + 8192;
    const u16* wv = wk + 8192;
    const float* bq = br ? bq1f : bq0f;
    const float* bk = br ? bk1f : bk0f;
    const float* bv = br ? bv1f : bv0f;
    u16* q = br ? q1 : q0;  u16* k = br ? k1 : k0;  u16* v = br ? v1 : v0;

    const int t = threadIdx.x, w = t >> 6, lane = t & 63;
    const int quad = lane >> 4, l15 = lane & 15;
    const float* xb = x + ((size_t)b << 19);

    for (int idx = t; idx < 8192; idx += 256) {
        const int c = idx >> 6, n = idx & 63;
        xt_s[n * 136 + c] = f2bf(xb[((size_t)c << 12) + n0 + n]);
    }
    __syncthreads();

    short8 ax[4];
#pragma unroll
    for (int cc = 0; cc < 4; ++cc)
        ax[cc] = *(const short8*)&xt_s[(w * 16 + l15) * 136 + quad * 8 + cc * 32];

    float mv[4] = {1.f, 1.f, 1.f, 1.f};
    if (br) {
#pragma unroll
        for (int r = 0; r < 4; ++r)
            mv[r] = mask[((size_t)b << 12) + n0 + w * 16 + quad * 4 + r];
    }

    // Q and K: D[n][i], i-cols = this half's 32; Q scaled by log2e
#pragma unroll
    for (int qk = 0; qk < 2; ++qk) {
        const u16* wsel = qk ? wk : wq;
        const float* bb = qk ? bk : bq;
        u16* o = qk ? k : q;
        const float qscale = qk ? 1.0f : LOG2E;
#pragma unroll
        for (int nsh = 0; nsh < 2; ++nsh) {
            const int ns = half * 2 + nsh;
            floatx4 acc = {0.f, 0.f, 0.f, 0.f};
            const u16* wp = wsel + (ns * 16 + l15) * 128 + quad * 8;
#pragma unroll
            for (int cc = 0; cc < 4; ++cc)
                acc = MFMA16(ax[cc], *(const short8*)(wp + cc * 32), acc);
            const float bias_i = bb[ns * 16 + l15];
#pragma unroll
            for (int r = 0; r < 4; ++r) {
                const float val = (acc[r] + bias_i) * mv[r] * qscale;
                o[((size_t)b << 18) + (size_t)(n0 + w * 16 + quad * 4 + r) * 64
                  + ns * 16 + l15] = f2bf(val);
            }
        }
    }

    // V: D[i][n], n-cols = this half's 32
    short8 aw[4];
#pragma unroll
    for (int cc = 0; cc < 4; ++cc)
        aw[cc] = *(const short8*)(wv + (w * 16 + l15) * 128 + quad * 8 + cc * 32);
    float bvr[4];
#pragma unroll
    for (int r = 0; r < 4; ++r) bvr[r] = bv[w * 16 + quad * 4 + r];
#pragma unroll
    for (int nsh = 0; nsh < 2; ++nsh) {
        const int ns = half * 2 + nsh;
        floatx4 acc = {0.f, 0.f, 0.f, 0.f};
#pragma unroll
        for (int cc = 0; cc < 4; ++cc)
            acc = MFMA16(aw[cc],
                *(const short8*)&xt_s[(ns * 16 + l15) * 136 + quad * 8 + cc * 32], acc);
#pragma unroll
        for (int r = 0; r < 4; ++r) {
            v[((size_t)b << 18) + ((size_t)(w * 16 + quad * 4 + r) << 12)
              + n0 + ns * 16 + l15] = f2bf(acc[r] + bvr[r]);
        }
    }
}

// ---------------------------------------------------------------------------
// K2: attention.  [R6 version — best measured flash, <=43 us]
// P stays in registers (cvt_pk + permlane redistribution).
// kt/vt: stride-64 XOR-granule-swizzled LDS via global_load_lds with
// pre-swizzled global source. Explicit vmcnt(0)+sched_barrier before each
// __syncthreads (LDS-DMA ordering — R4 raced without it).
// Denominator via MFMA with A=ones. NSP=4: grid 512 = 2 blocks/CU, NIT=16.
// NO cross-block fusion (R7: device-scope fences/atomics cost 6x — reverted).
// ---------------------------------------------------------------------------
__global__ __launch_bounds__(512, 4) void k_flash(
    const u16* __restrict__ Q0, const u16* __restrict__ K0,
    const u16* __restrict__ V0,
    const u16* __restrict__ Q1, const u16* __restrict__ K1,
    const u16* __restrict__ V1,
    u16* __restrict__ num, float* __restrict__ den)
{
    constexpr int NIT = 4096 / NSP / 64;     // 16 j-iters per block

    // K dbuf @0,4096 | V dbuf @8192,12288 (stride-64 swizzled)
    // tail phase reuses all 18432 as [wave][32][72] O^T staging
    __shared__ __align__(16) u16 smem[18432];

    const int flat = blockIdx.x;
    const int g = flat & 31, tile = flat >> 5;
    const int b = g >> 3, br = (g >> 2) & 1, sp = g & 3;
    const int z = br * NSP + sp;
    const int qb = tile * 256;
    const size_t base = ((size_t)b << 18);
    const u16* Q = (br ? Q1 : Q0) + base;
    const u16* K = (br ? K1 : K0) + base;
    const u16* V = (br ? V1 : V0) + base;
    u16* numo = num + (size_t)z * SZ_P + base;
    float* deno = den + z * 16384 + b * 4096;

    const int t = threadIdx.x, w = t >> 6, lane = t & 63;
    const int quad = lane >> 4, l15 = lane & 15;
    const int pw = w * 32 * 72;

    // staging: lane covers row r0, pre-swizzled granule gx so that the
    // linear lane*16B LDS write of global_load_lds lands on swz(row,g).
    const int r0 = t >> 3;
    const int gx = (t & 7) ^ ((t >> 3) & 7);
    const u16* Kp0 = K + (size_t)r0 * 64 + gx * 8;
    const u16* Vp0 = V + ((size_t)r0 << 12) + gx * 8;
    u16* kw = smem + w * 512;          // wave-uniform LDS bases (buffer 0)
    u16* vw = smem + 8192 + w * 512;

    short8 aq[2][2];
#pragma unroll
    for (int t2 = 0; t2 < 2; ++t2)
#pragma unroll
        for (int s = 0; s < 2; ++s)
            aq[t2][s] = *(const short8*)(Q + (size_t)(qb + w * 32 + t2 * 16 + l15) * 64
                                         + s * 32 + quad * 8);

    floatx4 oacc[4][2];
#pragma unroll
    for (int it = 0; it < 4; ++it)
#pragma unroll
        for (int t2 = 0; t2 < 2; ++t2) oacc[it][t2] = (floatx4){0.f, 0.f, 0.f, 0.f};
    floatx4 dacc4[2];
    dacc4[0] = (floatx4){0.f, 0.f, 0.f, 0.f};
    dacc4[1] = (floatx4){0.f, 0.f, 0.f, 0.f};
    const short8 vone = {(short)0x3F80, (short)0x3F80, (short)0x3F80, (short)0x3F80,
                         (short)0x3F80, (short)0x3F80, (short)0x3F80, (short)0x3F80};

    const int roff = tile & (NIT - 1);
    const int m_beg = sp * (4096 / NSP);

    {   // prologue: fill buffer 0
        const int m0 = m_beg + (roff << 6);
        gload16(Kp0 + (size_t)m0 * 64, kw);
        gload16(Vp0 + m0, vw);
    }

    for (int j = 0; j < NIT; ++j) {
        const int cur = j & 1;
        // Drain this wave's outstanding LDS-DMA BEFORE the barrier; barrier
        // then guarantees all waves' DMA landed (compiler won't do this).
        asm volatile("s_waitcnt vmcnt(0)" ::: "memory");
        __builtin_amdgcn_sched_barrier(0);
        __syncthreads();
        if (j + 1 < NIT) {
            const int mn = m_beg + (((roff + j + 1) & (NIT - 1)) << 6);
            gload16(Kp0 + (size_t)mn * 64, kw + (cur ^ 1) * 4096);
            gload16(Vp0 + mn, vw + (cur ^ 1) * 4096);
        }
        const u16* kt = smem + cur * 4096;
        const u16* vt = smem + 8192 + cur * 4096;

        // Per s-chunk (32 m): S' = K Q^T tiles + exp2, pack bf16 in-register,
        // permlane-redistribute to PV B-fragments, then PV + denominator MFMAs.
#pragma unroll
        for (int s = 0; s < 2; ++s) {
            unsigned int w0[2][2], w1[2][2];   // [mtl][t2] packed (e0,e1),(e2,e3)
#pragma unroll
            for (int mtl = 0; mtl < 2; ++mtl) {
                const int mt = s * 2 + mtl;
                const int ko = swz(mt * 16 + l15, quad);
                const short8 ka0 = *(const short8*)(kt + ko);
                const short8 ka1 = *(const short8*)(kt + (ko ^ 32)); // granule quad^4
#pragma unroll
                for (int t2 = 0; t2 < 2; ++t2) {
                    floatx4 acc = {0.f, 0.f, 0.f, 0.f};
                    __builtin_amdgcn_s_setprio(1);
                    acc = MFMA16(ka0, aq[t2][0], acc);
                    acc = MFMA16(ka1, aq[t2][1], acc);
                    __builtin_amdgcn_s_setprio(0);
                    const float e0 = __builtin_amdgcn_exp2f(acc[0]);
                    const float e1 = __builtin_amdgcn_exp2f(acc[1]);
                    const float e2 = __builtin_amdgcn_exp2f(acc[2]);
                    const float e3 = __builtin_amdgcn_exp2f(acc[3]);
                    w0[mtl][t2] = cvtpk(e0, e1);
                    w1[mtl][t2] = cvtpk(e2, e3);
                }
            }
            short8 pb[2];
#pragma unroll
            for (int t2 = 0; t2 < 2; ++t2) {
                unsigned int a0 = w0[0][t2], b0 = w0[1][t2];
                unsigned int a1 = w1[0][t2], b1 = w1[1][t2];
                plswap32(a0, b0); plswap16(a0, b0);   // a0=d0, b0=d2
                plswap32(a1, b1); plswap16(a1, b1);   // a1=d1, b1=d3
                union { unsigned int u[4]; short8 s8; } cv;
                cv.u[0] = a0; cv.u[1] = a1; cv.u[2] = b0; cv.u[3] = b1;
                pb[t2] = cv.s8;
            }
            __builtin_amdgcn_s_setprio(1);
#pragma unroll
            for (int it = 0; it < 4; ++it) {
                const short8 va = *(const short8*)(vt + swz(it * 16 + l15, s * 4 + quad));
#pragma unroll
                for (int t2 = 0; t2 < 2; ++t2)
                    oacc[it][t2] = MFMA16(va, pb[t2], oacc[it][t2]);
            }
            // denominator: A=ones -> D[r][q] = sum_m P[m][q] (all r equal)
            dacc4[0] = MFMA16(vone, pb[0], dacc4[0]);
            dacc4[1] = MFMA16(vone, pb[1], dacc4[1]);
            __builtin_amdgcn_s_setprio(0);
        }
    }

    // denominator partials (every lane holds the full column sum; r's equal)
    if (quad == 0) {
#pragma unroll
        for (int t2 = 0; t2 < 2; ++t2)
            deno[qb + w * 32 + t2 * 16 + l15] = dacc4[t2][0];
    }

    // O^T (C: row=i-local, col=q-local) -> smem (reused) as [q-local][i]
    __syncthreads();   // all waves done with kt/vt before aliasing (no DMA pending)
#pragma unroll
    for (int it = 0; it < 4; ++it)
#pragma unroll
        for (int t2 = 0; t2 < 2; ++t2) {
            *(uint2*)&smem[pw + (t2 * 16 + l15) * 72 + it * 16 + quad * 4] =
                make_uint2(cvtpk(oacc[it][t2][0], oacc[it][t2][1]),
                           cvtpk(oacc[it][t2][2], oacc[it][t2][3]));
        }
    __syncthreads();
#pragma unroll
    for (int ch = t; ch < 2048; ch += 512) {
        const int row = ch >> 3, cg = ch & 7;
        *(short8*)(numo + (size_t)(qb + row) * 64 + cg * 8) =
            *(const short8*)&smem[(row >> 5) * 2304 + (row & 31) * 72 + cg * 8];
    }
}

// ---------------------------------------------------------------------------
// K3: epilogue + split-K(xNSP) reduce; n-tile 16, grid (256,4).  [R2 version]
// ---------------------------------------------------------------------------
__global__ __launch_bounds__(256) void k_epi(
    const u16* __restrict__ num, const float* __restrict__ den,
    const u16* __restrict__ wbf,
    const float* __restrict__ gWl, const float* __restrict__ betaWl,
    const float* __restrict__ bW, const float* __restrict__ gW,
    const float* __restrict__ betaW,
    const float* __restrict__ x, float* __restrict__ out)
{
    __shared__ __align__(16) u16 yl_s[16 * 72];
    __shared__ __align__(16) u16 ynl_s[16 * 72];
    __shared__ __align__(16) u16 yy_s[16 * 72];
    const int b = blockIdx.y, n0 = blockIdx.x * 16;
    const int t = threadIdx.x, w = t >> 6, lane = t & 63;
    const int quad = lane >> 4, l15 = lane & 15;
    const size_t ybase = ((size_t)b << 18) + (size_t)n0 * 64;

    if (t < 128) {
        const int row = t >> 3, cg = t & 7;
        float dn = 0.f, dl = 0.f;
#pragma unroll
        for (int sp = 0; sp < NSP; ++sp) {
            dn += den[sp * 16384 + b * 4096 + n0 + row];
            dl += den[(NSP + sp) * 16384 + b * 4096 + n0 + row];
        }
        const float inl = 1.0f / dn, ilo = 1.0f / dl;
        float an[8] = {0, 0, 0, 0, 0, 0, 0, 0}, al[8] = {0, 0, 0, 0, 0, 0, 0, 0};
#pragma unroll
        for (int sp = 0; sp < NSP; ++sp) {
            const short8 vn = *(const short8*)(num + (size_t)sp * SZ_P + ybase + row * 64 + cg * 8);
            const short8 vl = *(const short8*)(num + (size_t)(NSP + sp) * SZ_P + ybase + row * 64 + cg * 8);
#pragma unroll
            for (int j = 0; j < 8; ++j) {
                an[j] += bf2f((u16)vn[j]);
                al[j] += bf2f((u16)vl[j]);
            }
        }
        short8 ynl8, yl8;
#pragma unroll
        for (int j = 0; j < 8; ++j) {
            ynl8[j] = (short)f2bf(an[j] * inl);
            yl8[j]  = (short)f2bf(al[j] * ilo);
        }
        *(short8*)&ynl_s[row * 72 + cg * 8] = ynl8;
        *(short8*)&yl_s[row * 72 + cg * 8] = yl8;
    }
    __syncthreads();
    const float rsq = rsqrtf(1.0f + 1e-5f);
    const u16* wblW = wbf + 49152;
    const u16* wbW  = wbf + 53248;

    // E1: yy[n][io] = bn(relu(wWl . y_l)) + y_nl
    {
        const short8 a0 = *(const short8*)(wblW + (w * 16 + l15) * 64 + quad * 8);
        const short8 a1 = *(const short8*)(wblW + (w * 16 + l15) * 64 + 32 + quad * 8);
        float sc[4], bt[4];
#pragma unroll
        for (int r = 0; r < 4; ++r) {
            const int io = w * 16 + quad * 4 + r;
            sc[r] = gWl[io] * rsq;
            bt[r] = betaWl[io];
        }
        floatx4 acc = {0.f, 0.f, 0.f, 0.f};
        const u16* bp_ = &yl_s[l15 * 72 + quad * 8];
        acc = MFMA16(a0, *(const short8*)bp_, acc);
        acc = MFMA16(a1, *(const short8*)(bp_ + 32), acc);
#pragma unroll
        for (int r = 0; r < 4; ++r) {
            const int io = w * 16 + quad * 4 + r;
            float val = fmaxf(acc[r], 0.f) * sc[r] + bt[r];
            val += bf2f(ynl_s[l15 * 72 + io]);
            yy_s[l15 * 72 + io] = f2bf(val);
        }
    }
    __syncthreads();

    // E2: out[c][n] = bn(relu(wW . yy + bW)) + x
#pragma unroll
    for (int rb = 0; rb < 2; ++rb) {
        const int c0 = rb * 64 + w * 16;
        const short8 a0 = *(const short8*)(wbW + (c0 + l15) * 64 + quad * 8);
        const short8 a1 = *(const short8*)(wbW + (c0 + l15) * 64 + 32 + quad * 8);
        float bs[4], sc[4], bt[4];
#pragma unroll
        for (int r = 0; r < 4; ++r) {
            const int c = c0 + quad * 4 + r;
            bs[r] = bW[c];
            sc[r] = gW[c] * rsq;
            bt[r] = betaW[c];
        }
        floatx4 acc = {0.f, 0.f, 0.f, 0.f};
        const u16* bp_ = &yy_s[l15 * 72 + quad * 8];
        acc = MFMA16(a0, *(const short8*)bp_, acc);
        acc = MFMA16(a1, *(const short8*)(bp_ + 32), acc);
#pragma unroll
        for (int r = 0; r < 4; ++r) {
            const int c = c0 + quad * 4 + r;
            float val = fmaxf(acc[r] + bs[r], 0.f) * sc[r] + bt[r];
            const size_t xi = ((size_t)b << 19) + ((size_t)c << 12) + n0 + l15;
            out[xi] = val + x[xi];
        }
    }
}

// ---------------------------------------------------------------------------
extern "C" void kernel_launch(void* const* d_in, const int* in_sizes, int n_in,
                              void* d_out, int out_size, void* d_ws, size_t ws_size,
                              hipStream_t stream) {
    const float* x      = (const float*)d_in[0];
    const float* mask   = (const float*)d_in[1];
    const float* wt_nl  = (const float*)d_in[2];  const float* bt_nl = (const float*)d_in[3];
    const float* wp_nl  = (const float*)d_in[4];  const float* bp_nl = (const float*)d_in[5];
    const float* wt_l   = (const float*)d_in[6];  const float* bt_l  = (const float*)d_in[7];
    const float* wp_l   = (const float*)d_in[8];  const float* bp_l  = (const float*)d_in[9];
    const float* wg_nl  = (const float*)d_in[10]; const float* bg_nl = (const float*)d_in[11];
    const float* wg_l   = (const float*)d_in[12]; const float* bg_l  = (const float*)d_in[13];
    const float* wW     = (const float*)d_in[14]; const float* bW    = (const float*)d_in[15];
    const float* gW     = (const float*)d_in[16]; const float* betaW = (const float*)d_in[17];
    const float* wWl    = (const float*)d_in[18]; const float* gWl   = (const float*)d_in[19];
    const float* betaWl = (const float*)d_in[20];

    // ws: wbf 120KB + 6 qkv (12.6MB) + num 2*NSP x 2MB (16.8MB) + den 512KB
    u16* ws  = (u16*)d_ws;
    u16* wbf = ws;                  // 61440
    u16* q0  = wbf + 61440;
    u16* k0  = q0 + SZ_P;
    u16* v0  = k0 + SZ_P;
    u16* q1  = v0 + SZ_P;
    u16* k1  = q1 + SZ_P;
    u16* v1  = k1 + SZ_P;
    u16* num = v1 + SZ_P;           // 2*NSP x SZ_P (z = br*NSP+sp)
    float* den = (float*)(num + (size_t)2 * NSP * SZ_P);  // 2*NSP x 16384 fp32

    k_prep_w<<<dim3(240), 256, 0, stream>>>(wt_nl, wp_nl, wg_nl,
                                            wt_l, wp_l, wg_l, wWl, wW, wbf);
    k_proj<<<dim3(64, 4, 4), 256, 0, stream>>>(x, mask, wbf,
        bt_nl, bp_nl, bg_nl, bt_l, bp_l, bg_l,
        q0, k0, v0, q1, k1, v1);
    k_flash<<<dim3(512), 512, 0, stream>>>(q0, k0, v0, q1, k1, v1, num, den);
    k_epi<<<dim3(256, 4), 256, 0, stream>>>(num, den, wbf, gWl, betaWl,
                                            bW, gW, betaW, x, (float*)d_out);
}